// Round 12
// baseline (905.902 us; speedup 1.0000x reference)
//
#include <hip/hip_runtime.h>
#include <stdint.h>
#include <math.h>

// PatchCore 1-NN: pool -> bf16 emb/coreset -> 256x256-tile MFMA GEMM-min
// single-barrier counted-vmcnt pipeline (3 LDS buffers) + XOR bank swizzle -> sqrt.
// B=8, C=1024, H=W=32, N=8192, M=32768, K=1024

#define N_TOT 8192
#define M_TOT 32768
#define EPS_ 1e-12f

typedef short bf16x8 __attribute__((ext_vector_type(8)));
typedef float f32x4 __attribute__((ext_vector_type(4)));

__device__ __forceinline__ unsigned short f2bf_rne(float f) {
    unsigned u = __float_as_uint(f);
    u += 0x7fffu + ((u >> 16) & 1u);
    return (unsigned short)(u >> 16);
}
__device__ __forceinline__ float bf2f(unsigned short h) {
    return __uint_as_float(((unsigned)h) << 16);
}

// ---------------- init: d2min = +inf bits, x2 = 0 ----------------
__global__ void init_kernel(unsigned* __restrict__ d2u, float* __restrict__ x2) {
    int i = blockIdx.x * blockDim.x + threadIdx.x;
    if (i < N_TOT) { d2u[i] = 0x7F800000u; x2[i] = 0.0f; }
}

// ---------------- pool 3x3 + transpose to [N,C] bf16 + partial x2 ----------------
__global__ __launch_bounds__(256) void pool_kernel(const float* __restrict__ feat,
                                                   unsigned short* __restrict__ emb,
                                                   float* __restrict__ x2) {
    int bid = blockIdx.x;
    int h  = bid & 31;
    int cc = (bid >> 5) & 31;
    int b  = bid >> 10;
    int tid = threadIdx.x;
    __shared__ float lds[32 * 97];

    const float* base = feat + ((size_t)(b * 1024 + cc * 32)) * 1024;
    int g0 = (h - 1) * 32;
    #pragma unroll
    for (int it = 0; it < 12; ++it) {
        int e = tid + it * 256;
        int ci = e / 96;
        int j  = e - ci * 96;
        int g  = g0 + j;
        float v = 0.0f;
        if (g >= 0 && g < 1024) v = base[(size_t)ci * 1024 + g];
        lds[ci * 97 + j] = v;
    }
    __syncthreads();

    int c  = tid & 31;
    int wb = tid >> 5;
    const float inv9 = 1.0f / 9.0f;
    #pragma unroll
    for (int i = 0; i < 4; ++i) {
        int w = wb + i * 8;
        float s = 0.0f;
        #pragma unroll
        for (int rr = 0; rr < 3; ++rr) {
            int rb = c * 97 + rr * 32 + w;
            s += lds[rb];
            if (w > 0)  s += lds[rb - 1];
            if (w < 31) s += lds[rb + 1];
        }
        float p = s * inv9;
        unsigned short bh = f2bf_rne(p);
        int n = b * 1024 + h * 32 + w;
        emb[(size_t)n * 1024 + cc * 32 + c] = bh;
        float pf = bf2f(bh);
        float sq = pf * pf;
        #pragma unroll
        for (int off = 1; off < 32; off <<= 1) sq += __shfl_xor(sq, off);
        if (c == 0) atomicAdd(&x2[n], sq);
    }
}

// ---------------- coreset -> bf16 + y2 (wave per row, no LDS) ----------------
// grid: 8192 blocks x 256 threads (4 waves = 4 rows per block)
__global__ __launch_bounds__(256) void cs_kernel(const float* __restrict__ cs,
                                                 unsigned short* __restrict__ csb,
                                                 float* __restrict__ y2) {
    int row  = blockIdx.x * 4 + (threadIdx.x >> 6);
    int lane = threadIdx.x & 63;
    const float4* src = reinterpret_cast<const float4*>(cs + (size_t)row * 1024);
    ushort4* dst = reinterpret_cast<ushort4*>(csb + (size_t)row * 1024);
    float s = 0.0f;
    #pragma unroll
    for (int it = 0; it < 4; ++it) {
        float4 v = src[lane + it * 64];
        ushort4 o;
        o.x = f2bf_rne(v.x); o.y = f2bf_rne(v.y);
        o.z = f2bf_rne(v.z); o.w = f2bf_rne(v.w);
        dst[lane + it * 64] = o;
        float a = bf2f(o.x), b = bf2f(o.y), c = bf2f(o.z), d = bf2f(o.w);
        s += a * a + b * b + c * c + d * d;
    }
    #pragma unroll
    for (int off = 1; off < 64; off <<= 1) s += __shfl_xor(s, off);
    if (lane == 0) y2[row] = s;
}

// ---------------- GEMM-min: 256x256 tile, BK=32, 8 waves, 3-buffer single-barrier pipeline ----
// grid: 32 emb-tiles x 128 cs-tiles = 4096 blocks, 512 threads.
// LDS buffer b: A [256 rows][4 x 16B slots, XOR-swizzled] then B same. 3 x 32KB = 96KB.
// Swizzle (both sides, rule 21): slot(r, chunk c) = c ^ ((r>>1)&3).
// Iteration u: vmcnt(4) [tile u confirmed; tile u+1 stays in flight] -> barrier ->
//   sched_barrier(0) [pins ds_reads below the barrier: cross-wave staging completion
//   is only established AT the barrier] -> STAGE tile u+2 [overwrites buf read at
//   iter u-1; barrier-separated] -> ds_reads buf[u%3] -> MFMA (compiler emits
//   fine-grained lgkmcnt per fragment -> each wave starts MFMA as soon as its own
//   data lands; LDS pipe overlaps MFMA pipe across waves).

#define STAGE(BUF, TT) do {                                                              \
    int t_ = (TT);                                                                       \
    _Pragma("unroll")                                                                    \
    for (int s_ = 0; s_ < 2; ++s_) {                                                     \
        __builtin_amdgcn_global_load_lds(                                                \
            (const __attribute__((address_space(1))) void*)(gA + (size_t)(s_ * 128 + rowq) * 1024 + t_ * 32 + ch * 8), \
            (__attribute__((address_space(3))) void*)(&lds[(BUF) * 16384 + s_ * 4096 + tid * 8]), 16, 0, 0); \
        __builtin_amdgcn_global_load_lds(                                                \
            (const __attribute__((address_space(1))) void*)(gB + (size_t)(s_ * 128 + rowq) * 1024 + t_ * 32 + ch * 8), \
            (__attribute__((address_space(3))) void*)(&lds[(BUF) * 16384 + 8192 + s_ * 4096 + tid * 8]), 16, 0, 0); \
    }                                                                                    \
} while (0)

#define READS_MFMA(BCUR) do {                                                            \
    bf16x8 af[8], bv[4];                                                                 \
    const unsigned short* pA = &lds[(BCUR) * 16384 + (wmBase + fr) * 32 + sx];           \
    const unsigned short* pB = &lds[(BCUR) * 16384 + 8192 + (wnBase + fr) * 32 + sx];    \
    _Pragma("unroll")                                                                    \
    for (int m = 0; m < 8; ++m) af[m] = *reinterpret_cast<const bf16x8*>(pA + m * 512);  \
    _Pragma("unroll")                                                                    \
    for (int n = 0; n < 4; ++n) bv[n] = *reinterpret_cast<const bf16x8*>(pB + n * 512);  \
    __builtin_amdgcn_s_setprio(1);                                                       \
    _Pragma("unroll")                                                                    \
    for (int m = 0; m < 8; ++m)                                                          \
        _Pragma("unroll")                                                                \
        for (int n = 0; n < 4; ++n)                                                      \
            acc[m][n] = __builtin_amdgcn_mfma_f32_16x16x32_bf16(af[m], bv[n], acc[m][n], 0, 0, 0); \
    __builtin_amdgcn_s_setprio(0);                                                       \
} while (0)

#define GEMM_ITER(BCUR, BSTG, TN) do {                                                   \
    asm volatile("s_waitcnt vmcnt(4)" ::: "memory");                                     \
    __builtin_amdgcn_s_barrier();                                                        \
    __builtin_amdgcn_sched_barrier(0);                                                   \
    STAGE(BSTG, TN);                                                                     \
    READS_MFMA(BCUR);                                                                    \
} while (0)

__global__ __launch_bounds__(512, 2) void gemm_min_kernel(const unsigned short* __restrict__ emb,
                                                          const unsigned short* __restrict__ csb,
                                                          const float* __restrict__ x2,
                                                          const float* __restrict__ y2,
                                                          unsigned* __restrict__ d2u) {
    __shared__ unsigned short lds[49152]; // 3 x (A 8192 + B 8192) shorts = 96 KB

    int bid = blockIdx.x;
    // XCD-aware supertile walk: XCD owns 16 cs-tiles; 4x4 supertiles (4MB) fit L2.
    int xcd   = bid & 7;
    int local = bid >> 3;        // 0..511
    int st    = local >> 4;      // 0..31
    int idx   = local & 15;
    int si = idx >> 2, sj = idx & 3;
    int emb_tile = (st & 7) * 4 + si;             // 0..31
    int cs_tile  = xcd * 16 + (st >> 3) * 4 + sj; // 0..127
    int nb = emb_tile * 256;
    int mb = cs_tile * 256;

    int tid  = threadIdx.x;
    int lane = tid & 63;
    int wid  = tid >> 6;         // 0..7
    int wmBase = (wid >> 2) * 128;
    int wnBase = (wid & 3) * 64;

    // staging addressing
    int rowq = tid >> 2;                          // 0..127
    int ch   = (tid & 3) ^ ((tid >> 3) & 3);      // swizzled source chunk
    const unsigned short* gA = emb + (size_t)nb * 1024;
    const unsigned short* gB = csb + (size_t)mb * 1024;

    // fragment read addressing
    int fr = lane & 15;
    int kq = lane >> 4;
    int sx = (kq ^ ((fr >> 1) & 3)) * 8;          // swizzled slot (shorts)

    f32x4 acc[8][4];
    #pragma unroll
    for (int m = 0; m < 8; ++m)
        #pragma unroll
        for (int n = 0; n < 4; ++n) acc[m][n] = (f32x4){0.f, 0.f, 0.f, 0.f};

    // prologue: stage K0 -> buf0, K1 -> buf1 (8 loads in flight)
    STAGE(0, 0);
    STAGE(1, 1);

    // main loop: iters 0..29, triple-unrolled for static buffer bases
    #pragma unroll 1
    for (int u = 0; u < 30; u += 3) {
        GEMM_ITER(0, 2, u + 2);
        GEMM_ITER(1, 0, u + 3);
        GEMM_ITER(2, 1, u + 4);
    }
    // tail: tile30 in buf0 (vmcnt(4): tile31 stays in flight), tile31 in buf1
    asm volatile("s_waitcnt vmcnt(4)" ::: "memory");
    __builtin_amdgcn_s_barrier();
    __builtin_amdgcn_sched_barrier(0);
    READS_MFMA(0);
    asm volatile("s_waitcnt vmcnt(0)" ::: "memory");
    __builtin_amdgcn_s_barrier();
    __builtin_amdgcn_sched_barrier(0);
    READS_MFMA(1);

    // epilogue: d2 = x2[row] + y2[col] - 2*dot; min over 64 cols of this wave
    // C/D layout: col = lane&15, row = (lane>>4)*4 + reg  [m89]
    int cc = lane & 15;
    int rq = (lane >> 4) * 4;
    float y2v[4];
    #pragma unroll
    for (int n = 0; n < 4; ++n) y2v[n] = y2[mb + wnBase + n * 16 + cc];

    #pragma unroll
    for (int m = 0; m < 8; ++m) {
        #pragma unroll
        for (int j = 0; j < 4; ++j) {
            float v = y2v[0] - 2.0f * acc[m][0][j];
            #pragma unroll
            for (int n = 1; n < 4; ++n) v = fminf(v, y2v[n] - 2.0f * acc[m][n][j]);
            int grow = nb + wmBase + m * 16 + rq + j;
            float d2 = x2[grow] + v;
            d2 = fmaxf(d2, EPS_);
            #pragma unroll
            for (int off = 1; off < 16; off <<= 1) d2 = fminf(d2, __shfl_xor(d2, off));
            if (cc == 0) atomicMin(&d2u[grow], __float_as_uint(d2));
        }
    }
}

// ---------------- finalize ----------------
__global__ void sqrt_kernel(const unsigned* __restrict__ d2u, float* __restrict__ out) {
    int i = blockIdx.x * blockDim.x + threadIdx.x;
    if (i < N_TOT) out[i] = sqrtf(__uint_as_float(d2u[i]));
}

extern "C" void kernel_launch(void* const* d_in, const int* in_sizes, int n_in,
                              void* d_out, int out_size, void* d_ws, size_t ws_size,
                              hipStream_t stream) {
    const float* feat = (const float*)d_in[0];   // [8,1024,32,32] fp32
    const float* cs   = (const float*)d_in[1];   // [32768,1024] fp32
    float* out = (float*)d_out;                  // [8192] fp32

    char* ws = (char*)d_ws;
    unsigned short* emb = (unsigned short*)ws;                          // 16 MB
    unsigned short* csb = (unsigned short*)(ws + 16777216);             // 64 MB
    float* x2 = (float*)(ws + 16777216 + 67108864);
    float* y2 = x2 + N_TOT;
    unsigned* d2u = (unsigned*)(y2 + M_TOT);

    init_kernel<<<N_TOT / 256, 256, 0, stream>>>(d2u, x2);
    pool_kernel<<<8192, 256, 0, stream>>>(feat, emb, x2);
    cs_kernel<<<M_TOT / 4, 256, 0, stream>>>(cs, csb, y2);
    gemm_min_kernel<<<4096, 512, 0, stream>>>(emb, csb, x2, y2, d2u);
    sqrt_kernel<<<N_TOT / 256, 256, 0, stream>>>(d2u, out);
}

// Round 13
// 890.989 us; speedup vs baseline: 1.0167x; 1.0167x over previous
//
#include <hip/hip_runtime.h>
#include <stdint.h>
#include <math.h>

// PatchCore 1-NN: pool -> bf16 emb/coreset -> 256x256-tile MFMA GEMM-min
// 4-phase interleaved K-loop (T3/T4): 3 LDS buffers, counted vmcnt, XOR swizzle -> sqrt.
// B=8, C=1024, H=W=32, N=8192, M=32768, K=1024

#define N_TOT 8192
#define M_TOT 32768
#define EPS_ 1e-12f

typedef short bf16x8 __attribute__((ext_vector_type(8)));
typedef float f32x4 __attribute__((ext_vector_type(4)));

__device__ __forceinline__ unsigned short f2bf_rne(float f) {
    unsigned u = __float_as_uint(f);
    u += 0x7fffu + ((u >> 16) & 1u);
    return (unsigned short)(u >> 16);
}
__device__ __forceinline__ float bf2f(unsigned short h) {
    return __uint_as_float(((unsigned)h) << 16);
}

// ---------------- init: d2min = +inf bits, x2 = 0 ----------------
__global__ void init_kernel(unsigned* __restrict__ d2u, float* __restrict__ x2) {
    int i = blockIdx.x * blockDim.x + threadIdx.x;
    if (i < N_TOT) { d2u[i] = 0x7F800000u; x2[i] = 0.0f; }
}

// ---------------- pool 3x3 + transpose to [N,C] bf16 + partial x2 ----------------
__global__ __launch_bounds__(256) void pool_kernel(const float* __restrict__ feat,
                                                   unsigned short* __restrict__ emb,
                                                   float* __restrict__ x2) {
    int bid = blockIdx.x;
    int h  = bid & 31;
    int cc = (bid >> 5) & 31;
    int b  = bid >> 10;
    int tid = threadIdx.x;
    __shared__ float lds[32 * 97];

    const float* base = feat + ((size_t)(b * 1024 + cc * 32)) * 1024;
    int g0 = (h - 1) * 32;
    #pragma unroll
    for (int it = 0; it < 12; ++it) {
        int e = tid + it * 256;
        int ci = e / 96;
        int j  = e - ci * 96;
        int g  = g0 + j;
        float v = 0.0f;
        if (g >= 0 && g < 1024) v = base[(size_t)ci * 1024 + g];
        lds[ci * 97 + j] = v;
    }
    __syncthreads();

    int c  = tid & 31;
    int wb = tid >> 5;
    const float inv9 = 1.0f / 9.0f;
    #pragma unroll
    for (int i = 0; i < 4; ++i) {
        int w = wb + i * 8;
        float s = 0.0f;
        #pragma unroll
        for (int rr = 0; rr < 3; ++rr) {
            int rb = c * 97 + rr * 32 + w;
            s += lds[rb];
            if (w > 0)  s += lds[rb - 1];
            if (w < 31) s += lds[rb + 1];
        }
        float p = s * inv9;
        unsigned short bh = f2bf_rne(p);
        int n = b * 1024 + h * 32 + w;
        emb[(size_t)n * 1024 + cc * 32 + c] = bh;
        float pf = bf2f(bh);
        float sq = pf * pf;
        #pragma unroll
        for (int off = 1; off < 32; off <<= 1) sq += __shfl_xor(sq, off);
        if (c == 0) atomicAdd(&x2[n], sq);
    }
}

// ---------------- coreset -> bf16 + y2 (wave per row, no LDS) ----------------
__global__ __launch_bounds__(256) void cs_kernel(const float* __restrict__ cs,
                                                 unsigned short* __restrict__ csb,
                                                 float* __restrict__ y2) {
    int row  = blockIdx.x * 4 + (threadIdx.x >> 6);
    int lane = threadIdx.x & 63;
    const float4* src = reinterpret_cast<const float4*>(cs + (size_t)row * 1024);
    ushort4* dst = reinterpret_cast<ushort4*>(csb + (size_t)row * 1024);
    float s = 0.0f;
    #pragma unroll
    for (int it = 0; it < 4; ++it) {
        float4 v = src[lane + it * 64];
        ushort4 o;
        o.x = f2bf_rne(v.x); o.y = f2bf_rne(v.y);
        o.z = f2bf_rne(v.z); o.w = f2bf_rne(v.w);
        dst[lane + it * 64] = o;
        float a = bf2f(o.x), b = bf2f(o.y), c = bf2f(o.z), d = bf2f(o.w);
        s += a * a + b * b + c * c + d * d;
    }
    #pragma unroll
    for (int off = 1; off < 64; off <<= 1) s += __shfl_xor(s, off);
    if (lane == 0) y2[row] = s;
}

// ---------------- GEMM-min: 256x256 tile, BK=32, 8 waves, 4-phase pipeline ----------------
// grid: 32 emb-tiles x 128 cs-tiles = 4096 blocks, 512 threads.
// 3 LDS buffers (96KB); swizzle: slot(r, chunk c) = c ^ ((r>>1)&3) (both sides).
// Iteration t (4 phases): phase q = { ds_read 2 A-frags (+4 B-frags at q=0, held in
// regs) ; issue 1 of K-tile t+2's 4 staging loads ; sched0 ; s_barrier ; sched0 ;
// setprio(1) ; 8 MFMA (C-quadrant q) ; setprio(0) ; sched0 ; [q=3: vmcnt(4)] ;
// s_barrier }. Phase-locking overlaps one wave's LDS reads with other waves' MFMA
// clusters (T3); vmcnt(4) once/iter keeps K-tile t+2's loads in flight across all
// barriers (T4). Ledger: prologue 8 outstanding; iter t issues 4 (phases 0-3),
// retires 4 (exactly K-tile t+1) at phase-3 end; tail 4 -> 0.
// Write-after-read: wave's phase reads complete before its MFMA (hw lgkmcnt) ->
// before it crosses the trailing barrier -> before any wave's next-iter stage issue.

#define STAGE(BUF, TT) do {                                                              \
    int t_ = (TT);                                                                       \
    _Pragma("unroll")                                                                    \
    for (int s_ = 0; s_ < 2; ++s_) {                                                     \
        __builtin_amdgcn_global_load_lds(                                                \
            (const __attribute__((address_space(1))) void*)(gA + (size_t)(s_ * 128 + rowq) * 1024 + t_ * 32 + ch * 8), \
            (__attribute__((address_space(3))) void*)(&lds[(BUF) * 16384 + s_ * 4096 + tid * 8]), 16, 0, 0); \
        __builtin_amdgcn_global_load_lds(                                                \
            (const __attribute__((address_space(1))) void*)(gB + (size_t)(s_ * 128 + rowq) * 1024 + t_ * 32 + ch * 8), \
            (__attribute__((address_space(3))) void*)(&lds[(BUF) * 16384 + 8192 + s_ * 4096 + tid * 8]), 16, 0, 0); \
    }                                                                                    \
} while (0)

// one staging load: MTX 0=A 1=B, HALF 0=rows 0..127, 1=rows 128..255
#define STAGE_ONE(BSTG, TT, MTX, HALF)                                                   \
    __builtin_amdgcn_global_load_lds(                                                    \
        (const __attribute__((address_space(1))) void*)(((MTX) ? gB : gA) + (size_t)((HALF) * 128 + rowq) * 1024 + (TT) * 32 + ch * 8), \
        (__attribute__((address_space(3))) void*)(&lds[(BSTG) * 16384 + (MTX) * 8192 + (HALF) * 4096 + tid * 8]), 16, 0, 0)

#define PHASE_CORE(Q, A0, A1) do {                                                       \
    __builtin_amdgcn_sched_barrier(0);                                                   \
    __builtin_amdgcn_s_barrier();                                                        \
    __builtin_amdgcn_sched_barrier(0);                                                   \
    __builtin_amdgcn_s_setprio(1);                                                       \
    _Pragma("unroll")                                                                    \
    for (int n = 0; n < 4; ++n) {                                                        \
        acc[2*(Q)][n]   = __builtin_amdgcn_mfma_f32_16x16x32_bf16(A0, bv[n], acc[2*(Q)][n], 0, 0, 0);   \
        acc[2*(Q)+1][n] = __builtin_amdgcn_mfma_f32_16x16x32_bf16(A1, bv[n], acc[2*(Q)+1][n], 0, 0, 0); \
    }                                                                                    \
    __builtin_amdgcn_s_setprio(0);                                                       \
    __builtin_amdgcn_sched_barrier(0);                                                   \
} while (0)

// One K-tile iteration: read buf BCUR, stage K-tile TT into BSTG (if DOSTAGE),
// VMN: 4 = steady-state vmcnt(4), 0 = drain, -1 = none.
#define ITER4(BCUR, BSTG, TT, DOSTAGE, VMN) do {                                         \
    const unsigned short* pA = &lds[(BCUR) * 16384 + aoff];                              \
    const unsigned short* pB = &lds[(BCUR) * 16384 + boff];                              \
    bf16x8 bv[4];                                                                        \
    _Pragma("unroll")                                                                    \
    for (int n = 0; n < 4; ++n) bv[n] = *reinterpret_cast<const bf16x8*>(pB + n * 512);  \
    bf16x8 a0 = *reinterpret_cast<const bf16x8*>(pA + 0 * 512);                          \
    bf16x8 a1 = *reinterpret_cast<const bf16x8*>(pA + 1 * 512);                          \
    if (DOSTAGE) STAGE_ONE(BSTG, TT, 0, 0);                                              \
    PHASE_CORE(0, a0, a1);                                                               \
    __builtin_amdgcn_s_barrier();                                                        \
    a0 = *reinterpret_cast<const bf16x8*>(pA + 2 * 512);                                 \
    a1 = *reinterpret_cast<const bf16x8*>(pA + 3 * 512);                                 \
    if (DOSTAGE) STAGE_ONE(BSTG, TT, 1, 0);                                              \
    PHASE_CORE(1, a0, a1);                                                               \
    __builtin_amdgcn_s_barrier();                                                        \
    a0 = *reinterpret_cast<const bf16x8*>(pA + 4 * 512);                                 \
    a1 = *reinterpret_cast<const bf16x8*>(pA + 5 * 512);                                 \
    if (DOSTAGE) STAGE_ONE(BSTG, TT, 0, 1);                                              \
    PHASE_CORE(2, a0, a1);                                                               \
    __builtin_amdgcn_s_barrier();                                                        \
    a0 = *reinterpret_cast<const bf16x8*>(pA + 6 * 512);                                 \
    a1 = *reinterpret_cast<const bf16x8*>(pA + 7 * 512);                                 \
    if (DOSTAGE) STAGE_ONE(BSTG, TT, 1, 1);                                              \
    PHASE_CORE(3, a0, a1);                                                               \
    if ((VMN) == 4) asm volatile("s_waitcnt vmcnt(4)" ::: "memory");                     \
    if ((VMN) == 0) asm volatile("s_waitcnt vmcnt(0)" ::: "memory");                     \
    __builtin_amdgcn_s_barrier();                                                        \
} while (0)

__global__ __launch_bounds__(512, 2) void gemm_min_kernel(const unsigned short* __restrict__ emb,
                                                          const unsigned short* __restrict__ csb,
                                                          const float* __restrict__ x2,
                                                          const float* __restrict__ y2,
                                                          unsigned* __restrict__ d2u) {
    __shared__ unsigned short lds[49152]; // 3 x (A 8192 + B 8192) shorts = 96 KB

    int bid = blockIdx.x;
    // XCD-aware supertile walk: XCD owns 16 cs-tiles; 4x4 supertiles (4MB) fit L2.
    int xcd   = bid & 7;
    int local = bid >> 3;        // 0..511
    int st    = local >> 4;      // 0..31
    int idx   = local & 15;
    int si = idx >> 2, sj = idx & 3;
    int emb_tile = (st & 7) * 4 + si;             // 0..31
    int cs_tile  = xcd * 16 + (st >> 3) * 4 + sj; // 0..127
    int nb = emb_tile * 256;
    int mb = cs_tile * 256;

    int tid  = threadIdx.x;
    int lane = tid & 63;
    int wid  = tid >> 6;         // 0..7
    int wmBase = (wid >> 2) * 128;
    int wnBase = (wid & 3) * 64;

    // staging addressing
    int rowq = tid >> 2;                          // 0..127
    int ch   = (tid & 3) ^ ((tid >> 3) & 3);      // swizzled source chunk
    const unsigned short* gA = emb + (size_t)nb * 1024;
    const unsigned short* gB = csb + (size_t)mb * 1024;

    // fragment read addressing
    int fr = lane & 15;
    int kq = lane >> 4;
    int sx = (kq ^ ((fr >> 1) & 3)) * 8;          // swizzled slot (shorts)
    int aoff = (wmBase + fr) * 32 + sx;
    int boff = 8192 + (wnBase + fr) * 32 + sx;

    f32x4 acc[8][4];
    #pragma unroll
    for (int m = 0; m < 8; ++m)
        #pragma unroll
        for (int n = 0; n < 4; ++n) acc[m][n] = (f32x4){0.f, 0.f, 0.f, 0.f};

    // prologue: stage K0 -> buf0, K1 -> buf1 (8 loads in flight); confirm K0, keep K1 flying
    STAGE(0, 0);
    STAGE(1, 1);
    asm volatile("s_waitcnt vmcnt(4)" ::: "memory");
    __builtin_amdgcn_s_barrier();

    // main loop: iters 0..29 read K-tile t from buf t%3, stage K-tile t+2 into buf (t+2)%3
    #pragma unroll 1
    for (int t = 0; t < 30; t += 3) {
        ITER4(0, 2, t + 2, true, 4);
        ITER4(1, 0, t + 3, true, 4);
        ITER4(2, 1, t + 4, true, 4);
    }
    // tail: K30 in buf0 (drain K31 at end), K31 in buf1
    ITER4(0, 0, 0, false, 0);
    ITER4(1, 0, 0, false, -1);

    // epilogue: d2 = x2[row] + y2[col] - 2*dot; min over 64 cols of this wave
    // C/D layout: col = lane&15, row = (lane>>4)*4 + reg  [m89]
    int cc = lane & 15;
    int rq = (lane >> 4) * 4;
    float y2v[4];
    #pragma unroll
    for (int n = 0; n < 4; ++n) y2v[n] = y2[mb + wnBase + n * 16 + cc];

    #pragma unroll
    for (int m = 0; m < 8; ++m) {
        #pragma unroll
        for (int j = 0; j < 4; ++j) {
            float v = y2v[0] - 2.0f * acc[m][0][j];
            #pragma unroll
            for (int n = 1; n < 4; ++n) v = fminf(v, y2v[n] - 2.0f * acc[m][n][j]);
            int grow = nb + wmBase + m * 16 + rq + j;
            float d2 = x2[grow] + v;
            d2 = fmaxf(d2, EPS_);
            #pragma unroll
            for (int off = 1; off < 16; off <<= 1) d2 = fminf(d2, __shfl_xor(d2, off));
            if (cc == 0) atomicMin(&d2u[grow], __float_as_uint(d2));
        }
    }
}

// ---------------- finalize ----------------
__global__ void sqrt_kernel(const unsigned* __restrict__ d2u, float* __restrict__ out) {
    int i = blockIdx.x * blockDim.x + threadIdx.x;
    if (i < N_TOT) out[i] = sqrtf(__uint_as_float(d2u[i]));
}

extern "C" void kernel_launch(void* const* d_in, const int* in_sizes, int n_in,
                              void* d_out, int out_size, void* d_ws, size_t ws_size,
                              hipStream_t stream) {
    const float* feat = (const float*)d_in[0];   // [8,1024,32,32] fp32
    const float* cs   = (const float*)d_in[1];   // [32768,1024] fp32
    float* out = (float*)d_out;                  // [8192] fp32

    char* ws = (char*)d_ws;
    unsigned short* emb = (unsigned short*)ws;                          // 16 MB
    unsigned short* csb = (unsigned short*)(ws + 16777216);             // 64 MB
    float* x2 = (float*)(ws + 16777216 + 67108864);
    float* y2 = x2 + N_TOT;
    unsigned* d2u = (unsigned*)(y2 + M_TOT);

    init_kernel<<<N_TOT / 256, 256, 0, stream>>>(d2u, x2);
    pool_kernel<<<8192, 256, 0, stream>>>(feat, emb, x2);
    cs_kernel<<<M_TOT / 4, 256, 0, stream>>>(cs, csb, y2);
    gemm_min_kernel<<<4096, 512, 0, stream>>>(emb, csb, x2, y2, d2u);
    sqrt_kernel<<<N_TOT / 256, 256, 0, stream>>>(d2u, out);
}